// Round 1
// baseline (8046.375 us; speedup 1.0000x reference)
//
#include <hip/hip_runtime.h>
#include <stdint.h>

typedef uint32_t u32;
typedef uint16_t u16;
typedef __attribute__((ext_vector_type(8))) short bf16x8;
typedef __attribute__((ext_vector_type(4))) float f32x4;

__device__ __forceinline__ u16 f2bf(float f) {
  u32 u = __builtin_bit_cast(u32, f);
  return (u16)((u + 0x7FFFu + ((u >> 16) & 1u)) >> 16);
}
__device__ __forceinline__ u32 pack2bf(float a, float b) {
  return (u32)f2bf(a) | ((u32)f2bf(b) << 16);
}
__device__ __forceinline__ uint4 pack8bf(float4 a, float4 b) {
  uint4 r;
  r.x = pack2bf(a.x, a.y); r.y = pack2bf(a.z, a.w);
  r.z = pack2bf(b.x, b.y); r.w = pack2bf(b.z, b.w);
  return r;
}
__device__ __forceinline__ float sigmoid_(float x) { return 1.0f / (1.0f + __expf(-x)); }
__device__ __forceinline__ float tanh_(float x) { return 1.0f - 2.0f / (1.0f + __expf(2.0f * x)); }

// ---------------------------------------------------------------------------
// Persistent LSTM: grid 256 = 16 unit-groups (ug) x 16 batch-groups (bg).
// WG (ug,bg): 32 hidden units x 16 batches. w_hh slice lives in VGPRs
// (A-fragments, bf16). Per step: stage h(t-1) [512 x 16 bf16] from global to
// LDS, 32 MFMA per wave, lane-local cell update, store 1KB h-slice, flag sync
// within the 16-WG batch column (device-scope atomics + acquire/release
// fences; correctness does not depend on XCD placement).
// Row interleave: LDS/logical row r = 4*unit_local + gate, so C-frag reg g of
// lane (q,n) is gate g of unit (tile*4+q), batch (bg*16+n).
// ---------------------------------------------------------------------------
__global__ __launch_bounds__(256, 2) void lstm_kernel(
    const int* __restrict__ trg, const float* __restrict__ w_ih,
    const float* __restrict__ w_hh, const float* __restrict__ b_ih,
    const float* __restrict__ b_hh, u16* __restrict__ h_buf,
    int* __restrict__ flags) {
  __shared__ u16 Bb[16 * 520];     // h(t-1): [n 16][k 512+8 pad] bf16
  __shared__ float Xl[16 * 513];   // x inputs: [n 16][t 512+1 pad] f32
  const int tid = threadIdx.x;
  const int wave = tid >> 6, lane = tid & 63;
  const int q = lane >> 4, n = lane & 15;
  const int bg = blockIdx.x & 15, ug = blockIdx.x >> 4;

  // ---- preload x = (float)trg for this bg's 16 batches ----
  #pragma unroll
  for (int c = 0; c < 4; ++c) {
    int e = c * 2048 + tid * 8;
    int rn = e >> 9, t0 = e & 511;
    const int* src = trg + (bg * 16 + rn) * 512 + t0;
    int4 a = *(const int4*)src;
    int4 b = *(const int4*)(src + 4);
    float* dst = &Xl[rn * 513 + t0];
    dst[0] = (float)a.x; dst[1] = (float)a.y; dst[2] = (float)a.z; dst[3] = (float)a.w;
    dst[4] = (float)b.x; dst[5] = (float)b.y; dst[6] = (float)b.z; dst[7] = (float)b.w;
  }

  // ---- preload w_hh slice as register-resident A fragments (bf16) ----
  // wave handles M-tiles {2*wave, 2*wave+1} (16 rows each).
  bf16x8 Areg[2][16];
  const int rit = lane & 15;  // A row within tile
  #pragma unroll
  for (int i = 0; i < 2; ++i) {
    int tile = wave * 2 + i;
    int grow = (rit & 3) * 512 + ug * 32 + tile * 4 + (rit >> 2);  // gate*512 + unit
    const float* wr = w_hh + (size_t)grow * 512;
    #pragma unroll
    for (int ks = 0; ks < 16; ++ks) {
      const float* p = wr + ks * 32 + q * 8;
      float4 f0 = *(const float4*)p;
      float4 f1 = *(const float4*)(p + 4);
      Areg[i][ks] = __builtin_bit_cast(bf16x8, pack8bf(f0, f1));
    }
  }

  // per-lane input weights & bias for the 2 tiles x 4 gates it will own
  float wi[2][4], bs[2][4];
  #pragma unroll
  for (int i = 0; i < 2; ++i) {
    int tile = wave * 2 + i;
    #pragma unroll
    for (int r = 0; r < 4; ++r) {
      int grow = r * 512 + ug * 32 + tile * 4 + q;
      wi[i][r] = w_ih[grow];
      bs[i][r] = b_ih[grow] + b_hh[grow];
    }
  }
  float cst[2] = {0.f, 0.f};  // cell state: unit tile*4+q, batch bg*16+n
  __syncthreads();

  for (int t = 1; t <= 511; ++t) {
    if (t > 1) {
      if (tid == 0) {
        int cnt = 0;
        while (__hip_atomic_load(&flags[(t - 1) * 16 + bg], __ATOMIC_RELAXED,
                                 __HIP_MEMORY_SCOPE_AGENT) < 16) {
          __builtin_amdgcn_s_sleep(1);
          if (++cnt > (1 << 22)) break;  // convert deadlock into wrong-answer
        }
      }
      __syncthreads();
      __builtin_amdgcn_fence(__ATOMIC_ACQUIRE, "agent");
    }
    // stage B = h(t-1)[512 x 16] for this bg (16KB), pad-aware
    {
      const u16* src = h_buf + (size_t)(((t - 1) & 1) * 16 + bg) * 8192;
      #pragma unroll
      for (int c = 0; c < 4; ++c) {
        int e = c * 2048 + tid * 8;
        int rn = e >> 9, k = e & 511;
        uint4 d = *(const uint4*)(src + e);
        *(uint4*)&Bb[rn * 520 + k] = d;
      }
    }
    __syncthreads();

    f32x4 acc[2] = {{0.f, 0.f, 0.f, 0.f}, {0.f, 0.f, 0.f, 0.f}};
    const u16* brow = &Bb[n * 520];
    #pragma unroll
    for (int ks = 0; ks < 16; ++ks) {
      bf16x8 bf = *(const bf16x8*)(brow + ks * 32 + q * 8);
      acc[0] = __builtin_amdgcn_mfma_f32_16x16x32_bf16(Areg[0][ks], bf, acc[0], 0, 0, 0);
      acc[1] = __builtin_amdgcn_mfma_f32_16x16x32_bf16(Areg[1][ks], bf, acc[1], 0, 0, 0);
    }

    float x = Xl[n * 513 + (t - 1)];
    u16* hdst = h_buf + (size_t)((t & 1) * 16 + bg) * 8192 + n * 512 + ug * 32 + q;
    #pragma unroll
    for (int i = 0; i < 2; ++i) {
      int tile = wave * 2 + i;
      float pi = acc[i][0] + x * wi[i][0] + bs[i][0];
      float pf = acc[i][1] + x * wi[i][1] + bs[i][1];
      float pg = acc[i][2] + x * wi[i][2] + bs[i][2];
      float po = acc[i][3] + x * wi[i][3] + bs[i][3];
      float ig = sigmoid_(pi), fg = sigmoid_(pf), og = sigmoid_(po);
      float gg = tanh_(pg);
      cst[i] = fg * cst[i] + ig * gg;
      float h = og * tanh_(cst[i]);
      hdst[tile * 4] = f2bf(h);
    }
    __syncthreads();  // drains all waves' h stores (vmcnt 0) before release
    if (tid == 0) {
      __builtin_amdgcn_fence(__ATOMIC_RELEASE, "agent");
      __hip_atomic_fetch_add(&flags[t * 16 + bg], 1, __ATOMIC_RELAXED,
                             __HIP_MEMORY_SCOPE_AGENT);
    }
  }
}

// ---------------------------------------------------------------------------
// Head GEMM: out[b][m] = sum_k A[m][k]*B[b][k] (+bias), A fp32 MxK, B bf16
// [256][K]. Tile M=128 per WG, N=256 full. mode 0: relu + bf16 out (fc1->z),
// mode 1: fp32 out (fc2). Out leading dim == M for both uses.
// ---------------------------------------------------------------------------
__global__ __launch_bounds__(256, 1) void head_gemm(
    const float* __restrict__ A, const u16* __restrict__ B,
    const float* __restrict__ bias, void* __restrict__ outv,
    int M, int K, int mode) {
  __shared__ u16 Ach[128 * 40];
  __shared__ u16 Bch[256 * 40];
  const int tid = threadIdx.x;
  const int wave = tid >> 6, lane = tid & 63;
  const int q = lane >> 4, l15 = lane & 15;
  const int mblk = blockIdx.x * 128;
  const int nch = K >> 5;
  f32x4 acc[2][16];
  #pragma unroll
  for (int i = 0; i < 2; ++i)
    #pragma unroll
    for (int nb = 0; nb < 16; ++nb) acc[i][nb] = (f32x4){0.f, 0.f, 0.f, 0.f};

  for (int ch = 0; ch < nch; ++ch) {
    __syncthreads();
    {  // A chunk: 128 rows x 32 k, fp32 -> bf16
      int row = tid >> 1, k = (tid & 1) * 16;
      const float* src = A + (size_t)(mblk + row) * K + ch * 32 + k;
      float4 f0 = *(const float4*)src;
      float4 f1 = *(const float4*)(src + 4);
      float4 f2 = *(const float4*)(src + 8);
      float4 f3 = *(const float4*)(src + 12);
      u16* dst = &Ach[row * 40 + k];
      *(uint4*)dst = pack8bf(f0, f1);
      *(uint4*)(dst + 8) = pack8bf(f2, f3);
    }
    #pragma unroll
    for (int c = 0; c < 4; ++c) {  // B chunk: 256 rows x 32 k bf16
      int e = c * 2048 + tid * 8;
      int nr = e >> 5, k = e & 31;
      uint4 d = *(const uint4*)(B + (size_t)nr * K + ch * 32 + k);
      *(uint4*)&Bch[nr * 40 + k] = d;
    }
    __syncthreads();
    bf16x8 a0 = *(const bf16x8*)&Ach[((wave * 2 + 0) * 16 + l15) * 40 + q * 8];
    bf16x8 a1 = *(const bf16x8*)&Ach[((wave * 2 + 1) * 16 + l15) * 40 + q * 8];
    #pragma unroll
    for (int nb = 0; nb < 16; ++nb) {
      bf16x8 bf = *(const bf16x8*)&Bch[(nb * 16 + l15) * 40 + q * 8];
      acc[0][nb] = __builtin_amdgcn_mfma_f32_16x16x32_bf16(a0, bf, acc[0][nb], 0, 0, 0);
      acc[1][nb] = __builtin_amdgcn_mfma_f32_16x16x32_bf16(a1, bf, acc[1][nb], 0, 0, 0);
    }
  }
  #pragma unroll
  for (int i = 0; i < 2; ++i) {
    int j0 = mblk + (wave * 2 + i) * 16 + q * 4;
    float4 bv = *(const float4*)(bias + j0);
    #pragma unroll
    for (int nb = 0; nb < 16; ++nb) {
      int b = nb * 16 + l15;
      f32x4 v = acc[i][nb];
      v[0] += bv.x; v[1] += bv.y; v[2] += bv.z; v[3] += bv.w;
      if (mode == 0) {
        v[0] = fmaxf(v[0], 0.f); v[1] = fmaxf(v[1], 0.f);
        v[2] = fmaxf(v[2], 0.f); v[3] = fmaxf(v[3], 0.f);
        u16* z = (u16*)outv;
        uint2 pk;
        pk.x = pack2bf(v[0], v[1]);
        pk.y = pack2bf(v[2], v[3]);
        *(uint2*)(z + (size_t)b * M + j0) = pk;
      } else {
        float* op = (float*)outv + (size_t)b * M + j0;
        float4 o;
        o.x = v[0]; o.y = v[1]; o.z = v[2]; o.w = v[3];
        *(float4*)op = o;
      }
    }
  }
}

// ---------------------------------------------------------------------------
// Workspace layout (bytes):
//   [0,        524288)  h_buf: [parity 2][bg 16][n 16][k 512] bf16
//   [524288,   557056)  flags: [t 512][bg 16] int
//   [557056,  1081344)  z: [256][1024] bf16
// ---------------------------------------------------------------------------
extern "C" void kernel_launch(void* const* d_in, const int* in_sizes, int n_in,
                              void* d_out, int out_size, void* d_ws, size_t ws_size,
                              hipStream_t stream) {
  (void)in_sizes; (void)n_in; (void)out_size; (void)ws_size;
  const int* trg = (const int*)d_in[2];
  const float* w_ih = (const float*)d_in[3];
  const float* w_hh = (const float*)d_in[4];
  const float* b_ih = (const float*)d_in[5];
  const float* b_hh = (const float*)d_in[6];
  const float* fc1_w = (const float*)d_in[7];
  const float* fc1_b = (const float*)d_in[8];
  const float* fc2_w = (const float*)d_in[9];
  const float* fc2_b = (const float*)d_in[10];

  u16* h_buf = (u16*)d_ws;
  int* flags = (int*)((char*)d_ws + 524288);
  u16* z = (u16*)((char*)d_ws + 557056);

  hipMemsetAsync(d_ws, 0, 262144, stream);                  // h parity 0 = h(0) = 0
  hipMemsetAsync((char*)d_ws + 524288, 0, 32768, stream);   // flags = 0

  lstm_kernel<<<256, 256, 0, stream>>>(trg, w_ih, w_hh, b_ih, b_hh, h_buf, flags);

  const u16* h_final = h_buf + 16 * 16 * 512;  // parity 1 == h(511), layout [b][512]
  head_gemm<<<8, 256, 0, stream>>>(fc1_w, h_final, fc1_b, (void*)z, 1024, 512, 0);
  head_gemm<<<250, 256, 0, stream>>>(fc2_w, z, fc2_b, d_out, 32000, 1024, 1);
}

// Round 2
// 1725.520 us; speedup vs baseline: 4.6632x; 4.6632x over previous
//
#include <hip/hip_runtime.h>
#include <stdint.h>

typedef uint32_t u32;
typedef uint16_t u16;
typedef __attribute__((ext_vector_type(8))) short bf16x8;
typedef __attribute__((ext_vector_type(4))) float f32x4;

__device__ __forceinline__ u16 f2bf(float f) {
  u32 u = __builtin_bit_cast(u32, f);
  return (u16)((u + 0x7FFFu + ((u >> 16) & 1u)) >> 16);
}
__device__ __forceinline__ u32 pack2bf(float a, float b) {
  return (u32)f2bf(a) | ((u32)f2bf(b) << 16);
}
__device__ __forceinline__ uint4 pack8bf(float4 a, float4 b) {
  uint4 r;
  r.x = pack2bf(a.x, a.y); r.y = pack2bf(a.z, a.w);
  r.z = pack2bf(b.x, b.y); r.w = pack2bf(b.z, b.w);
  return r;
}
__device__ __forceinline__ float sigmoid_(float x) { return 1.0f / (1.0f + __expf(-x)); }
__device__ __forceinline__ float tanh_(float x) { return 1.0f - 2.0f / (1.0f + __expf(2.0f * x)); }

// L3-coherent (cross-XCD) access helpers: sc0 sc1 = bypass L1+L2, the
// coherence point is the memory-side Infinity Cache shared by all XCDs.
// No bulk L2 writeback/invalidate needed (that was R1's 15.6us/step killer).
__device__ __forceinline__ void store_h_l3(u16* p, u32 v) {
  asm volatile("global_store_short %0, %1, off sc0 sc1" :: "v"(p), "v"(v) : "memory");
}
__device__ __forceinline__ u32 load_flag_l3(const int* p) {
  u32 v;
  asm volatile("global_load_dword %0, %1, off sc0 sc1\n\ts_waitcnt vmcnt(0)"
               : "=v"(v) : "v"(p) : "memory");
  return v;
}

// ---------------------------------------------------------------------------
// Persistent LSTM: grid 256 = 16 unit-groups (ug) x 16 batch-groups (bg).
// WG (ug,bg): 32 hidden units x 16 batches. w_hh slice lives in VGPRs
// (A-fragments, bf16). Per step: poll flag (all lanes, L3 load), stage
// h(t-1) [512 x 16 bf16] L3 -> LDS, 32 MFMA per wave, lane-local cell
// update, scattered u16 h stores (write-through to L3), drain, flag add.
// Row interleave: logical row r = 4*unit_local + gate, so C-frag reg g of
// lane (q,n) is gate g of unit (tile*4+q), batch (bg*16+n).
// ---------------------------------------------------------------------------
__global__ __launch_bounds__(256, 2) void lstm_kernel(
    const int* __restrict__ trg, const float* __restrict__ w_ih,
    const float* __restrict__ w_hh, const float* __restrict__ b_ih,
    const float* __restrict__ b_hh, u16* __restrict__ h_buf,
    int* __restrict__ flags) {
  __shared__ u16 Bb[16 * 520];     // h(t-1): [n 16][k 512+8 pad] bf16
  __shared__ float Xl[16 * 513];   // x inputs: [n 16][t 512+1 pad] f32
  const int tid = threadIdx.x;
  const int wave = tid >> 6, lane = tid & 63;
  const int q = lane >> 4, n = lane & 15;
  const int bg = blockIdx.x & 15, ug = blockIdx.x >> 4;

  // ---- preload x = (float)trg for this bg's 16 batches ----
  #pragma unroll
  for (int c = 0; c < 4; ++c) {
    int e = c * 2048 + tid * 8;
    int rn = e >> 9, t0 = e & 511;
    const int* src = trg + (bg * 16 + rn) * 512 + t0;
    int4 a = *(const int4*)src;
    int4 b = *(const int4*)(src + 4);
    float* dst = &Xl[rn * 513 + t0];
    dst[0] = (float)a.x; dst[1] = (float)a.y; dst[2] = (float)a.z; dst[3] = (float)a.w;
    dst[4] = (float)b.x; dst[5] = (float)b.y; dst[6] = (float)b.z; dst[7] = (float)b.w;
  }

  // ---- preload w_hh slice as register-resident A fragments (bf16) ----
  bf16x8 Areg[2][16];
  const int rit = lane & 15;  // A row within tile
  #pragma unroll
  for (int i = 0; i < 2; ++i) {
    int tile = wave * 2 + i;
    int grow = (rit & 3) * 512 + ug * 32 + tile * 4 + (rit >> 2);  // gate*512 + unit
    const float* wr = w_hh + (size_t)grow * 512;
    #pragma unroll
    for (int ks = 0; ks < 16; ++ks) {
      const float* p = wr + ks * 32 + q * 8;
      float4 f0 = *(const float4*)p;
      float4 f1 = *(const float4*)(p + 4);
      Areg[i][ks] = __builtin_bit_cast(bf16x8, pack8bf(f0, f1));
    }
  }

  // per-lane input weights & bias for the 2 tiles x 4 gates it will own
  float wi[2][4], bs[2][4];
  #pragma unroll
  for (int i = 0; i < 2; ++i) {
    int tile = wave * 2 + i;
    #pragma unroll
    for (int r = 0; r < 4; ++r) {
      int grow = r * 512 + ug * 32 + tile * 4 + q;
      wi[i][r] = w_ih[grow];
      bs[i][r] = b_ih[grow] + b_hh[grow];
    }
  }
  float cst[2] = {0.f, 0.f};  // cell state: unit tile*4+q, batch bg*16+n
  __syncthreads();

  for (int t = 1; t <= 511; ++t) {
    // ---- wait for h(t-1) to be published (all lanes poll, same address) ----
    if (t > 1) {
      const int* fp = &flags[(t - 1) * 16 + bg];
      int cnt = 0;
      u32 v;
      do {
        v = load_flag_l3(fp);
        if (++cnt > (1 << 20)) break;  // convert deadlock into wrong answer
      } while (v < 16u);
    }
    // ---- stage B = h(t-1)[512 x 16] for this bg (16KB) from L3 ----
    {
      const u16* src = h_buf + (size_t)(((t - 1) & 1) * 16 + bg) * 8192;
      const u16* p0 = src + 0 * 2048 + tid * 8;
      const u16* p1 = src + 1 * 2048 + tid * 8;
      const u16* p2 = src + 2 * 2048 + tid * 8;
      const u16* p3 = src + 3 * 2048 + tid * 8;
      uint4 d0, d1, d2, d3;
      asm volatile(
          "global_load_dwordx4 %0, %4, off sc0 sc1\n\t"
          "global_load_dwordx4 %1, %5, off sc0 sc1\n\t"
          "global_load_dwordx4 %2, %6, off sc0 sc1\n\t"
          "global_load_dwordx4 %3, %7, off sc0 sc1\n\t"
          "s_waitcnt vmcnt(0)"
          : "=&v"(d0), "=&v"(d1), "=&v"(d2), "=&v"(d3)
          : "v"(p0), "v"(p1), "v"(p2), "v"(p3)
          : "memory");
      #pragma unroll
      for (int c = 0; c < 4; ++c) {
        int e = c * 2048 + tid * 8;
        int rn = e >> 9, k = e & 511;
        uint4 d = (c == 0) ? d0 : (c == 1) ? d1 : (c == 2) ? d2 : d3;
        *(uint4*)&Bb[rn * 520 + k] = d;
      }
    }
    __syncthreads();

    f32x4 acc[2] = {{0.f, 0.f, 0.f, 0.f}, {0.f, 0.f, 0.f, 0.f}};
    const u16* brow = &Bb[n * 520];
    #pragma unroll
    for (int ks = 0; ks < 16; ++ks) {
      bf16x8 bf = *(const bf16x8*)(brow + ks * 32 + q * 8);
      acc[0] = __builtin_amdgcn_mfma_f32_16x16x32_bf16(Areg[0][ks], bf, acc[0], 0, 0, 0);
      acc[1] = __builtin_amdgcn_mfma_f32_16x16x32_bf16(Areg[1][ks], bf, acc[1], 0, 0, 0);
    }

    float x = Xl[n * 513 + (t - 1)];
    u16* hdst = h_buf + (size_t)((t & 1) * 16 + bg) * 8192 + n * 512 + ug * 32 + q;
    #pragma unroll
    for (int i = 0; i < 2; ++i) {
      int tile = wave * 2 + i;
      float pi = acc[i][0] + x * wi[i][0] + bs[i][0];
      float pf = acc[i][1] + x * wi[i][1] + bs[i][1];
      float pg = acc[i][2] + x * wi[i][2] + bs[i][2];
      float po = acc[i][3] + x * wi[i][3] + bs[i][3];
      float ig = sigmoid_(pi), fg = sigmoid_(pf), og = sigmoid_(po);
      float gg = tanh_(pg);
      cst[i] = fg * cst[i] + ig * gg;
      float h = og * tanh_(cst[i]);
      store_h_l3(hdst + tile * 4, (u32)f2bf(h));
    }
    asm volatile("s_waitcnt vmcnt(0)" ::: "memory");  // h stores acked at L3
    __syncthreads();  // all 4 waves' stores drained before the flag add
    if (tid == 0) {
      __hip_atomic_fetch_add(&flags[t * 16 + bg], 1, __ATOMIC_RELAXED,
                             __HIP_MEMORY_SCOPE_AGENT);
    }
  }
}

// ---------------------------------------------------------------------------
// Head GEMM: out[b][m] = sum_k A[m][k]*B[b][k] (+bias), A fp32 MxK, B bf16
// [256][K]. Tile M=128 per WG, N=256 full. mode 0: relu + bf16 out (fc1->z),
// mode 1: fp32 out (fc2). Out leading dim == M for both uses.
// ---------------------------------------------------------------------------
__global__ __launch_bounds__(256, 1) void head_gemm(
    const float* __restrict__ A, const u16* __restrict__ B,
    const float* __restrict__ bias, void* __restrict__ outv,
    int M, int K, int mode) {
  __shared__ u16 Ach[128 * 40];
  __shared__ u16 Bch[256 * 40];
  const int tid = threadIdx.x;
  const int wave = tid >> 6, lane = tid & 63;
  const int q = lane >> 4, l15 = lane & 15;
  const int mblk = blockIdx.x * 128;
  const int nch = K >> 5;
  f32x4 acc[2][16];
  #pragma unroll
  for (int i = 0; i < 2; ++i)
    #pragma unroll
    for (int nb = 0; nb < 16; ++nb) acc[i][nb] = (f32x4){0.f, 0.f, 0.f, 0.f};

  for (int ch = 0; ch < nch; ++ch) {
    __syncthreads();
    {  // A chunk: 128 rows x 32 k, fp32 -> bf16
      int row = tid >> 1, k = (tid & 1) * 16;
      const float* src = A + (size_t)(mblk + row) * K + ch * 32 + k;
      float4 f0 = *(const float4*)src;
      float4 f1 = *(const float4*)(src + 4);
      float4 f2 = *(const float4*)(src + 8);
      float4 f3 = *(const float4*)(src + 12);
      u16* dst = &Ach[row * 40 + k];
      *(uint4*)dst = pack8bf(f0, f1);
      *(uint4*)(dst + 8) = pack8bf(f2, f3);
    }
    #pragma unroll
    for (int c = 0; c < 4; ++c) {  // B chunk: 256 rows x 32 k bf16
      int e = c * 2048 + tid * 8;
      int nr = e >> 5, k = e & 31;
      uint4 d = *(const uint4*)(B + (size_t)nr * K + ch * 32 + k);
      *(uint4*)&Bch[nr * 40 + k] = d;
    }
    __syncthreads();
    bf16x8 a0 = *(const bf16x8*)&Ach[((wave * 2 + 0) * 16 + l15) * 40 + q * 8];
    bf16x8 a1 = *(const bf16x8*)&Ach[((wave * 2 + 1) * 16 + l15) * 40 + q * 8];
    #pragma unroll
    for (int nb = 0; nb < 16; ++nb) {
      bf16x8 bf = *(const bf16x8*)&Bch[(nb * 16 + l15) * 40 + q * 8];
      acc[0][nb] = __builtin_amdgcn_mfma_f32_16x16x32_bf16(a0, bf, acc[0][nb], 0, 0, 0);
      acc[1][nb] = __builtin_amdgcn_mfma_f32_16x16x32_bf16(a1, bf, acc[1][nb], 0, 0, 0);
    }
  }
  #pragma unroll
  for (int i = 0; i < 2; ++i) {
    int j0 = mblk + (wave * 2 + i) * 16 + q * 4;
    float4 bv = *(const float4*)(bias + j0);
    #pragma unroll
    for (int nb = 0; nb < 16; ++nb) {
      int b = nb * 16 + l15;
      f32x4 v = acc[i][nb];
      v[0] += bv.x; v[1] += bv.y; v[2] += bv.z; v[3] += bv.w;
      if (mode == 0) {
        v[0] = fmaxf(v[0], 0.f); v[1] = fmaxf(v[1], 0.f);
        v[2] = fmaxf(v[2], 0.f); v[3] = fmaxf(v[3], 0.f);
        u16* z = (u16*)outv;
        uint2 pk;
        pk.x = pack2bf(v[0], v[1]);
        pk.y = pack2bf(v[2], v[3]);
        *(uint2*)(z + (size_t)b * M + j0) = pk;
      } else {
        float* op = (float*)outv + (size_t)b * M + j0;
        float4 o;
        o.x = v[0]; o.y = v[1]; o.z = v[2]; o.w = v[3];
        *(float4*)op = o;
      }
    }
  }
}

// ---------------------------------------------------------------------------
// Workspace layout (bytes):
//   [0,        524288)  h_buf: [parity 2][bg 16][n 16][k 512] bf16
//   [524288,   557056)  flags: [t 512][bg 16] int
//   [557056,  1081344)  z: [256][1024] bf16
// ---------------------------------------------------------------------------
extern "C" void kernel_launch(void* const* d_in, const int* in_sizes, int n_in,
                              void* d_out, int out_size, void* d_ws, size_t ws_size,
                              hipStream_t stream) {
  (void)in_sizes; (void)n_in; (void)out_size; (void)ws_size;
  const int* trg = (const int*)d_in[2];
  const float* w_ih = (const float*)d_in[3];
  const float* w_hh = (const float*)d_in[4];
  const float* b_ih = (const float*)d_in[5];
  const float* b_hh = (const float*)d_in[6];
  const float* fc1_w = (const float*)d_in[7];
  const float* fc1_b = (const float*)d_in[8];
  const float* fc2_w = (const float*)d_in[9];
  const float* fc2_b = (const float*)d_in[10];

  u16* h_buf = (u16*)d_ws;
  int* flags = (int*)((char*)d_ws + 524288);
  u16* z = (u16*)((char*)d_ws + 557056);

  hipMemsetAsync(d_ws, 0, 262144, stream);                  // h parity 0 = h(0) = 0
  hipMemsetAsync((char*)d_ws + 524288, 0, 32768, stream);   // flags = 0

  lstm_kernel<<<256, 256, 0, stream>>>(trg, w_ih, w_hh, b_ih, b_hh, h_buf, flags);

  const u16* h_final = h_buf + 16 * 16 * 512;  // parity 1 == h(511), layout [b][512]
  head_gemm<<<8, 256, 0, stream>>>(fc1_w, h_final, fc1_b, (void*)z, 1024, 512, 0);
  head_gemm<<<250, 256, 0, stream>>>(fc2_w, z, fc2_b, d_out, 32000, 1024, 1);
}

// Round 6
// 1642.294 us; speedup vs baseline: 4.8995x; 1.0507x over previous
//
#include <hip/hip_runtime.h>
#include <stdint.h>

typedef uint32_t u32;
typedef uint16_t u16;
typedef __attribute__((ext_vector_type(8))) short bf16x8;
typedef __attribute__((ext_vector_type(4))) float f32x4;

__device__ __forceinline__ u16 f2bf(float f) {
  u32 u = __builtin_bit_cast(u32, f);
  return (u16)((u + 0x7FFFu + ((u >> 16) & 1u)) >> 16);
}
__device__ __forceinline__ u32 pack2bf(float a, float b) {
  return (u32)f2bf(a) | ((u32)f2bf(b) << 16);
}
__device__ __forceinline__ uint4 pack8bf(float4 a, float4 b) {
  uint4 r;
  r.x = pack2bf(a.x, a.y); r.y = pack2bf(a.z, a.w);
  r.z = pack2bf(b.x, b.y); r.w = pack2bf(b.z, b.w);
  return r;
}
__device__ __forceinline__ float sigmoid_(float x) { return 1.0f / (1.0f + __expf(-x)); }
__device__ __forceinline__ float tanh_(float x) { return 1.0f - 2.0f / (1.0f + __expf(2.0f * x)); }

// ---------------------------------------------------------------------------
// Persistent LSTM — R2's PROVEN coherence protocol (sc0 sc1 L3-coherent
// exchange, per-WG atomic count flags, barrier-gated phases; R2 passed at
// absmax 7.8e-3). R6 changes are value-neutral only:
//  * tile-interleave: A-row rit -> gate rit&3, unit-offset 2*(rit>>2)+i, so
//    lane q's two outputs are ADJACENT units wave*8+2q,+1 (one pack2bf dword).
//  * h store coalesced through LDS: lane writes dword to Hs[n*16+wave*4+q];
//    barrier; thread tid stores Hs[tid] -> h_buf (16 B-contig per 16 lanes,
//    full 64B lines). Kills R2's 4x write amplification (527MB WRITE_SIZE).
// h_buf layout/content is BIT-IDENTICAL to R2 -> absmax must reproduce.
// ---------------------------------------------------------------------------
__global__ __launch_bounds__(256, 2) void lstm_kernel(
    const int* __restrict__ trg, const float* __restrict__ w_ih,
    const float* __restrict__ w_hh, const float* __restrict__ b_ih,
    const float* __restrict__ b_hh, u16* __restrict__ h_buf,
    int* __restrict__ flags) {
  __shared__ u16 Bb[16 * 520];     // h(t-1): [n 16][k 512+8 pad] bf16
  __shared__ float Xl[16 * 513];   // x inputs: [n 16][t 512+1 pad] f32
  __shared__ u32 Hs[256];          // h(t) gather: [n 16][u32pos 16]
  const int tid = threadIdx.x;
  const int wave = tid >> 6, lane = tid & 63;
  const int q = lane >> 4, n = lane & 15;
  const int bg = blockIdx.x & 15, ug = blockIdx.x >> 4;

  // ---- preload x = (float)trg for this bg's 16 batches ----
  #pragma unroll
  for (int c = 0; c < 4; ++c) {
    int e = c * 2048 + tid * 8;
    int rn = e >> 9, t0 = e & 511;
    const int* src = trg + (bg * 16 + rn) * 512 + t0;
    int4 a = *(const int4*)src;
    int4 b = *(const int4*)(src + 4);
    float* dst = &Xl[rn * 513 + t0];
    dst[0] = (float)a.x; dst[1] = (float)a.y; dst[2] = (float)a.z; dst[3] = (float)a.w;
    dst[4] = (float)b.x; dst[5] = (float)b.y; dst[6] = (float)b.z; dst[7] = (float)b.w;
  }

  // ---- preload w_hh slice: tile-interleaved rows, NATURAL k packing ----
  // A-row rit of tile i -> gate rit&3, unit wave*8 + 2*(rit>>2) + i
  bf16x8 Areg[2][16];
  const int rit = lane & 15;
  #pragma unroll
  for (int i = 0; i < 2; ++i) {
    int grow = (rit & 3) * 512 + ug * 32 + wave * 8 + 2 * (rit >> 2) + i;
    const float* wr = w_hh + (size_t)grow * 512;
    #pragma unroll
    for (int ks = 0; ks < 16; ++ks) {
      const float* p = wr + ks * 32 + q * 8;
      float4 f0 = *(const float4*)p;
      float4 f1 = *(const float4*)(p + 4);
      Areg[i][ks] = __builtin_bit_cast(bf16x8, pack8bf(f0, f1));
    }
  }

  // per-lane input weights & bias: lane q, tile i -> unit wave*8 + 2q + i
  float wi[2][4], bs[2][4];
  #pragma unroll
  for (int i = 0; i < 2; ++i) {
    #pragma unroll
    for (int r = 0; r < 4; ++r) {
      int grow = r * 512 + ug * 32 + wave * 8 + q * 2 + i;
      wi[i][r] = w_ih[grow];
      bs[i][r] = b_ih[grow] + b_hh[grow];
    }
  }
  float cst[2] = {0.f, 0.f};  // cell state: units wave*8+2q+{0,1}, batch bg*16+n
  __syncthreads();

  for (int t = 1; t <= 511; ++t) {
    // ---- wait for h(t-1) published (R2 protocol: tid0 polls atomic count) ----
    if (t > 1) {
      if (tid == 0) {
        int cnt = 0;
        while (__hip_atomic_load(&flags[(t - 1) * 16 + bg], __ATOMIC_RELAXED,
                                 __HIP_MEMORY_SCOPE_AGENT) < 16) {
          if (++cnt > (1 << 22)) break;  // convert deadlock into wrong answer
        }
      }
      __syncthreads();
    }
    // ---- stage B = h(t-1)[512 x 16] for this bg (16KB) from L3 (sc0 sc1) ----
    {
      const u16* src = h_buf + (size_t)(((t - 1) & 1) * 16 + bg) * 8192;
      const u16* p0 = src + 0 * 2048 + tid * 8;
      const u16* p1 = src + 1 * 2048 + tid * 8;
      const u16* p2 = src + 2 * 2048 + tid * 8;
      const u16* p3 = src + 3 * 2048 + tid * 8;
      uint4 d0, d1, d2, d3;
      asm volatile(
          "global_load_dwordx4 %0, %4, off sc0 sc1\n\t"
          "global_load_dwordx4 %1, %5, off sc0 sc1\n\t"
          "global_load_dwordx4 %2, %6, off sc0 sc1\n\t"
          "global_load_dwordx4 %3, %7, off sc0 sc1\n\t"
          "s_waitcnt vmcnt(0)"
          : "=&v"(d0), "=&v"(d1), "=&v"(d2), "=&v"(d3)
          : "v"(p0), "v"(p1), "v"(p2), "v"(p3)
          : "memory");
      #pragma unroll
      for (int c = 0; c < 4; ++c) {
        int e = c * 2048 + tid * 8;
        int rn = e >> 9, k = e & 511;
        uint4 d = (c == 0) ? d0 : (c == 1) ? d1 : (c == 2) ? d2 : d3;
        *(uint4*)&Bb[rn * 520 + k] = d;
      }
    }
    __syncthreads();

    f32x4 acc[2] = {{0.f, 0.f, 0.f, 0.f}, {0.f, 0.f, 0.f, 0.f}};
    const u16* brow = &Bb[n * 520];
    #pragma unroll
    for (int ks = 0; ks < 16; ++ks) {
      bf16x8 bf = *(const bf16x8*)(brow + ks * 32 + q * 8);
      acc[0] = __builtin_amdgcn_mfma_f32_16x16x32_bf16(Areg[0][ks], bf, acc[0], 0, 0, 0);
      acc[1] = __builtin_amdgcn_mfma_f32_16x16x32_bf16(Areg[1][ks], bf, acc[1], 0, 0, 0);
    }

    float x = Xl[n * 513 + (t - 1)];
    float hv0, hv1;
    #pragma unroll
    for (int i = 0; i < 2; ++i) {
      float pi = acc[i][0] + x * wi[i][0] + bs[i][0];
      float pf = acc[i][1] + x * wi[i][1] + bs[i][1];
      float pg = acc[i][2] + x * wi[i][2] + bs[i][2];
      float po = acc[i][3] + x * wi[i][3] + bs[i][3];
      float ig = sigmoid_(pi), fg = sigmoid_(pf), og = sigmoid_(po);
      float gg = tanh_(pg);
      cst[i] = fg * cst[i] + ig * gg;
      float h = og * tanh_(cst[i]);
      if (i == 0) hv0 = h; else hv1 = h;
    }

    // ---- gather h(t) in LDS, then coalesced dword store (sc0 sc1) ----
    Hs[n * 16 + wave * 4 + q] = pack2bf(hv0, hv1);  // units wave*8+2q, +1
    __syncthreads();
    {
      u32 hv = Hs[tid];
      // u32 index: parity*65536 + (bg*16 + n')*256 + ug*16 + pos, n'=tid>>4
      u32* dst = (u32*)h_buf + (size_t)((t & 1) ? 65536 : 0) +
                 (size_t)(bg * 16 + (tid >> 4)) * 256 + ug * 16 + (tid & 15);
      asm volatile("global_store_dword %0, %1, off sc0 sc1\n\ts_waitcnt vmcnt(0)"
                   :: "v"(dst), "v"(hv) : "memory");
    }
    __syncthreads();  // all 256 stores drained before the flag add
    if (tid == 0) {
      __hip_atomic_fetch_add(&flags[t * 16 + bg], 1, __ATOMIC_RELAXED,
                             __HIP_MEMORY_SCOPE_AGENT);
    }
  }
}

// ---------------------------------------------------------------------------
// Head GEMM (R2's proven version): out[b][m] = sum_k A[m][k]*B[b][k] (+bias),
// A fp32 MxK, B bf16 [256][K]. M=128/WG, N=256. mode 0: relu+bf16 out (fc1),
// mode 1: fp32 out (fc2). Out leading dim == M for both uses.
// ---------------------------------------------------------------------------
__global__ __launch_bounds__(256, 1) void head_gemm(
    const float* __restrict__ A, const u16* __restrict__ B,
    const float* __restrict__ bias, void* __restrict__ outv,
    int M, int K, int mode) {
  __shared__ u16 Ach[128 * 40];
  __shared__ u16 Bch[256 * 40];
  const int tid = threadIdx.x;
  const int wave = tid >> 6, lane = tid & 63;
  const int q = lane >> 4, l15 = lane & 15;
  const int mblk = blockIdx.x * 128;
  const int nch = K >> 5;
  f32x4 acc[2][16];
  #pragma unroll
  for (int i = 0; i < 2; ++i)
    #pragma unroll
    for (int nb = 0; nb < 16; ++nb) acc[i][nb] = (f32x4){0.f, 0.f, 0.f, 0.f};

  for (int ch = 0; ch < nch; ++ch) {
    __syncthreads();
    {  // A chunk: 128 rows x 32 k, fp32 -> bf16
      int row = tid >> 1, k = (tid & 1) * 16;
      const float* src = A + (size_t)(mblk + row) * K + ch * 32 + k;
      float4 f0 = *(const float4*)src;
      float4 f1 = *(const float4*)(src + 4);
      float4 f2 = *(const float4*)(src + 8);
      float4 f3 = *(const float4*)(src + 12);
      u16* dst = &Ach[row * 40 + k];
      *(uint4*)dst = pack8bf(f0, f1);
      *(uint4*)(dst + 8) = pack8bf(f2, f3);
    }
    #pragma unroll
    for (int c = 0; c < 4; ++c) {  // B chunk: 256 rows x 32 k bf16
      int e = c * 2048 + tid * 8;
      int nr = e >> 5, k = e & 31;
      uint4 d = *(const uint4*)(B + (size_t)nr * K + ch * 32 + k);
      *(uint4*)&Bch[nr * 40 + k] = d;
    }
    __syncthreads();
    bf16x8 a0 = *(const bf16x8*)&Ach[((wave * 2 + 0) * 16 + l15) * 40 + q * 8];
    bf16x8 a1 = *(const bf16x8*)&Ach[((wave * 2 + 1) * 16 + l15) * 40 + q * 8];
    #pragma unroll
    for (int nb = 0; nb < 16; ++nb) {
      bf16x8 bf = *(const bf16x8*)&Bch[(nb * 16 + l15) * 40 + q * 8];
      acc[0][nb] = __builtin_amdgcn_mfma_f32_16x16x32_bf16(a0, bf, acc[0][nb], 0, 0, 0);
      acc[1][nb] = __builtin_amdgcn_mfma_f32_16x16x32_bf16(a1, bf, acc[1][nb], 0, 0, 0);
    }
  }
  #pragma unroll
  for (int i = 0; i < 2; ++i) {
    int j0 = mblk + (wave * 2 + i) * 16 + q * 4;
    float4 bv = *(const float4*)(bias + j0);
    #pragma unroll
    for (int nb = 0; nb < 16; ++nb) {
      int b = nb * 16 + l15;
      f32x4 v = acc[i][nb];
      v[0] += bv.x; v[1] += bv.y; v[2] += bv.z; v[3] += bv.w;
      if (mode == 0) {
        v[0] = fmaxf(v[0], 0.f); v[1] = fmaxf(v[1], 0.f);
        v[2] = fmaxf(v[2], 0.f); v[3] = fmaxf(v[3], 0.f);
        u16* z = (u16*)outv;
        uint2 pk;
        pk.x = pack2bf(v[0], v[1]);
        pk.y = pack2bf(v[2], v[3]);
        *(uint2*)(z + (size_t)b * M + j0) = pk;
      } else {
        float* op = (float*)outv + (size_t)b * M + j0;
        float4 o;
        o.x = v[0]; o.y = v[1]; o.z = v[2]; o.w = v[3];
        *(float4*)op = o;
      }
    }
  }
}

// ---------------------------------------------------------------------------
// Workspace layout (bytes):
//   [0,        524288)  h_buf: [parity 2][bg 16][n 16][k 512] bf16, natural
//   [524288,   557056)  flags: [t 512][bg 16] int, count of finished WGs
//   [557056,  1081344)  z: [256][1024] bf16
// ---------------------------------------------------------------------------
extern "C" void kernel_launch(void* const* d_in, const int* in_sizes, int n_in,
                              void* d_out, int out_size, void* d_ws, size_t ws_size,
                              hipStream_t stream) {
  (void)in_sizes; (void)n_in; (void)out_size; (void)ws_size;
  const int* trg = (const int*)d_in[2];
  const float* w_ih = (const float*)d_in[3];
  const float* w_hh = (const float*)d_in[4];
  const float* b_ih = (const float*)d_in[5];
  const float* b_hh = (const float*)d_in[6];
  const float* fc1_w = (const float*)d_in[7];
  const float* fc1_b = (const float*)d_in[8];
  const float* fc2_w = (const float*)d_in[9];
  const float* fc2_b = (const float*)d_in[10];

  u16* h_buf = (u16*)d_ws;
  int* flags = (int*)((char*)d_ws + 524288);
  u16* z = (u16*)((char*)d_ws + 557056);

  hipMemsetAsync(d_ws, 0, 262144, stream);                  // h parity 0 = h(0) = 0
  hipMemsetAsync((char*)d_ws + 524288, 0, 32768, stream);   // flags = 0

  lstm_kernel<<<256, 256, 0, stream>>>(trg, w_ih, w_hh, b_ih, b_hh, h_buf, flags);

  const u16* h_final = h_buf + 131072;  // parity 1 == h(511), layout [b][512]
  head_gemm<<<8, 256, 0, stream>>>(fc1_w, h_final, fc1_b, (void*)z, 1024, 512, 0);
  head_gemm<<<250, 256, 0, stream>>>(fc2_w, z, fc2_b, d_out, 32000, 1024, 1);
}